// Round 1
// baseline (361.326 us; speedup 1.0000x reference)
//
#include <hip/hip_runtime.h>

// B=8, S=128, R=192, C=192. 7-point stencil on index-clamped field.
// Round-3: S-axis register marching. Each thread produces SC=16 planes for its
// (b, j, 4-wide k strip). Sm/C/Sp planes rotate through registers (each plane
// row loaded once, not 3x); next-step loads (Sp, Rm, Rp, D) are issued one
// iteration ahead so HBM latency hides under the 56-FMA stencil of the current
// step. Grid 3072 blocks = 48 jg x 8 b x 8 chunks, XCD-contiguous swizzle.

#define BB 8
#define SS 128
#define RR 192
#define CC 192
#define PLANE (RR * CC)
#define SC 16
#define NCHUNK (SS / SC)             // 8
#define NWG (48 * BB * NCHUNK)       // 3072, divisible by 8 XCDs

typedef float v4f __attribute__((ext_vector_type(4)));

struct Row6 { float cm, w1, w2, w3, w4, cp; };

// 4-wide row with k-edge clamp fixups (used as Sm/Rm/Rp operand)
__device__ __forceinline__ v4f load_row4(const float* __restrict__ row, int k0,
                                         bool e0, bool e1)
{
    v4f c4 = *(const v4f*)(row + k0);
    c4.x = e0 ? c4.y : c4.x;
    c4.w = e1 ? c4.z : c4.w;
    return c4;
}

// 6-wide row (with C-window scalars) — used when the row will become center
__device__ __forceinline__ Row6 load_row6(const float* __restrict__ row, int k0,
                                          int kcm, int kcp, bool e0, bool e1)
{
    Row6 r;
    v4f c4 = *(const v4f*)(row + k0);
    r.cm = row[kcm];
    r.cp = row[kcp];
    r.w1 = e0 ? c4.y : c4.x;
    r.w2 = c4.y;
    r.w3 = c4.z;
    r.w4 = e1 ? c4.z : c4.w;
    return r;
}

__device__ __forceinline__ float stencil_pt(float pc, float pSm, float pSp,
                                            float pRm, float pRp,
                                            float pCm, float pCp, float d)
{
    const float inv2dx = 0.25f;        // 1/(2*2.0)
    const float inv2dy = 1.0f / 3.0f;  // 1/(2*1.5)
    const float inv2dz = 1.0f / 3.0f;
    const float invdx2 = 0.25f;        // 1/4.0
    const float invdy2 = 1.0f / 2.25f;
    const float invdz2 = 1.0f / 2.25f;

    float dcx = (pSp - pSm) * inv2dx;
    float dcy = (pRp - pRm) * inv2dy;
    float dcz = (pCp - pCm) * inv2dz;
    float F = dcx * dcx + dcy * dcy + dcz * dcz;
    float G = (pSp - 2.0f * pc + pSm) * invdx2
            + (pRp - 2.0f * pc + pRm) * invdy2
            + (pCp - 2.0f * pc + pCm) * invdz2;
    return -0.5f * F - d * G;
}

__global__ __launch_bounds__(192, 6) void flowp_kernel(
    const float* __restrict__ P,
    const float* __restrict__ D,
    float* __restrict__ out)
{
    const int tx = threadIdx.x;          // 0..47
    const int k0 = tx << 2;              // 0..188
    const bool e0 = (tx == 0);
    const bool e1 = (tx == 47);
    const int kcm = e0 ? 1 : k0 - 1;        // clamped k0-1
    const int kcp = e1 ? CC - 2 : k0 + 4;   // clamped k0+4

    // XCD-contiguous bijective swizzle: each XCD owns a contiguous run of
    // adjacent-j blocks (which share Rm/Rp marching-front rows in L2).
    const int wg    = blockIdx.x;
    const int swz   = (wg & 7) * (NWG / 8) + (wg >> 3);
    const int jg    = swz % 48;
    const int bc    = swz / 48;          // 0..63
    const int b     = bc & 7;
    const int chunk = bc >> 3;
    const int i0    = chunk * SC;

    const int j   = jg * 4 + threadIdx.y;            // 0..191
    const int cj  = min(max(j,     1), RR - 2);
    const int cjm = min(max(j - 1, 1), RR - 2);
    const int cjp = min(max(j + 1, 1), RR - 2);

    const float* Pb    = P + b * (SS * PLANE);
    const float* rowC  = Pb + cj  * CC;   // add plane*PLANE per step
    const float* rowJm = Pb + cjm * CC;
    const float* rowJp = Pb + cjp * CC;

    // clamped plane offsets: offC = clamp(i)*PLANE, offP = clamp(i+1)*PLANE
    const int pm = min(max(i0 - 1, 1), SS - 2);
    int offC = min(max(i0, 1), SS - 2) * PLANE;
    int offP = min(i0 + 1, SS - 2) * PLANE;

    // prologue: 3 S-planes + current-step Rm/Rp/D
    v4f  aM = load_row4(rowC + pm * PLANE, k0, e0, e1);
    Row6 aC = load_row6(rowC + offC, k0, kcm, kcp, e0, e1);
    Row6 aP = load_row6(rowC + offP, k0, kcm, kcp, e0, e1);
    v4f  Rm = load_row4(rowJm + offC, k0, e0, e1);
    v4f  Rp = load_row4(rowJp + offC, k0, e0, e1);

    int idxO = ((b * SS + i0) * RR + j) * CC + k0;   // unclamped out/D index
    v4f d4 = __builtin_nontemporal_load((const v4f*)(D + idxO));

#pragma unroll
    for (int s = 0; s < SC; ++s) {
        // prefetch next step: Rm/Rp at next center plane (offP), next Sp row
        // (offN), next D. Issued before the current stencil so the latency
        // hides under ~56 FMAs.
        const int offN = min(offP + PLANE, (SS - 2) * PLANE);
        v4f nRm = Rm, nRp = Rp, nD = d4;
        Row6 nC = aP;
        if (s < SC - 1) {
            nRm = load_row4(rowJm + offP, k0, e0, e1);
            nRp = load_row4(rowJp + offP, k0, e0, e1);
            nC  = load_row6(rowC + offN, k0, kcm, kcp, e0, e1);
            nD  = __builtin_nontemporal_load((const v4f*)(D + idxO + PLANE));
        }

        v4f o;
        //               pc     pSm   pSp    pRm   pRp   pCm    pCp    d
        o.x = stencil_pt(aC.w1, aM.x, aP.w1, Rm.x, Rp.x, aC.cm, aC.w2, d4.x);
        o.y = stencil_pt(aC.w2, aM.y, aP.w2, Rm.y, Rp.y, aC.w1, aC.w3, d4.y);
        o.z = stencil_pt(aC.w3, aM.z, aP.w3, Rm.z, Rp.z, aC.w2, aC.w4, d4.z);
        o.w = stencil_pt(aC.w4, aM.w, aP.w4, Rm.w, Rp.w, aC.w3, aC.cp, d4.w);
        __builtin_nontemporal_store(o, (v4f*)(out + idxO));

        // rotate S-planes: center becomes Sm (already k-fixed-up), Sp becomes
        // center, prefetched row becomes Sp.
        aM.x = aC.w1; aM.y = aC.w2; aM.z = aC.w3; aM.w = aC.w4;
        aC = aP; aP = nC;
        Rm = nRm; Rp = nRp; d4 = nD;
        offC = offP; offP = offN;
        idxO += PLANE;
    }
}

extern "C" void kernel_launch(void* const* d_in, const int* in_sizes, int n_in,
                              void* d_out, int out_size, void* d_ws, size_t ws_size,
                              hipStream_t stream) {
    const float* P = (const float*)d_in[1];
    const float* D = (const float*)d_in[2];
    float* out = (float*)d_out;

    dim3 block(48, 4, 1);      // 192 threads = 3 waves
    dim3 grid(NWG, 1, 1);      // 3072 blocks
    flowp_kernel<<<grid, block, 0, stream>>>(P, D, out);
}

// Round 3
// 340.580 us; speedup vs baseline: 1.0609x; 1.0609x over previous
//
#include <hip/hip_runtime.h>

// B=8, S=128, R=192, C=192. 7-point stencil on index-clamped field.
// Round-4: back to the flat round-0 structure (110 us) but with TWO i-planes
// per thread. All 16 loads are independent and issued up-front (MLP 9->16),
// center rows for planes i0-1..i0+2 are loaded once and shared between the
// two outputs (per-output vector loads 2.75 -> 1.75). TLP stays high:
// 24576 blocks / 73728 waves. No loop-carried chains (round-1's mistake).

#define BB 8
#define SS 128
#define RR 192
#define CC 192
#define PLANE (RR * CC)

typedef float v4f __attribute__((ext_vector_type(4)));

__device__ __forceinline__ v4f fix4(v4f c4, bool e0, bool e1)
{
    c4.x = e0 ? c4.y : c4.x;
    c4.w = e1 ? c4.z : c4.w;
    return c4;
}

__device__ __forceinline__ float stencil_pt(float pc, float pSm, float pSp,
                                            float pRm, float pRp,
                                            float pCm, float pCp, float d)
{
    const float inv2dx = 0.25f;        // 1/(2*2.0)
    const float inv2dy = 1.0f / 3.0f;  // 1/(2*1.5)
    const float inv2dz = 1.0f / 3.0f;
    const float invdx2 = 0.25f;        // 1/4.0
    const float invdy2 = 1.0f / 2.25f;
    const float invdz2 = 1.0f / 2.25f;

    float dcx = (pSp - pSm) * inv2dx;
    float dcy = (pRp - pRm) * inv2dy;
    float dcz = (pCp - pCm) * inv2dz;
    float F = dcx * dcx + dcy * dcy + dcz * dcz;
    float G = (pSp - 2.0f * pc + pSm) * invdx2
            + (pRp - 2.0f * pc + pRm) * invdy2
            + (pCp - 2.0f * pc + pCm) * invdz2;
    return -0.5f * F - d * G;
}

// block = (48, 4): tx covers C in float4 chunks, ty covers 4 rows.
// grid = (1, R/4, B*S/2): each thread emits outputs at i0 and i0+1.
__global__ __launch_bounds__(192) void flowp_kernel(
    const float* __restrict__ P,
    const float* __restrict__ D,
    float* __restrict__ out)
{
    const int tx = threadIdx.x;              // 0..47
    const int k0 = tx << 2;                  // 0..188
    const bool e0 = (tx == 0);
    const bool e1 = (tx == 47);
    const int kcm = e0 ? 1 : k0 - 1;         // clamped k0-1
    const int kcp = e1 ? CC - 2 : k0 + 4;    // clamped k0+4

    const int j  = blockIdx.y * 4 + threadIdx.y;  // 0..191
    const int bz = blockIdx.z;               // 0..511
    const int b  = bz >> 6;
    const int i0 = (bz & 63) << 1;           // 0,2,...,126
    const int i1 = i0 + 1;

    const int cj  = min(max(j,     1), RR - 2);
    const int cjm = min(max(j - 1, 1), RR - 2);
    const int cjp = min(max(j + 1, 1), RR - 2);

    // clamped plane indices for the 4 center rows (A=i0-1, B=i0, C=i0+1, Dp=i0+2)
    const int pA = min(max(i0 - 1, 1), SS - 2);
    const int pB = max(i0, 1);               // i0 <= 126 always
    const int pC = min(i1, SS - 2);
    const int pD = min(i0 + 2, SS - 2);

    const float* Pb  = P + b * (SS * PLANE);
    const float* rA  = Pb + pA * PLANE + cj  * CC;
    const float* rB  = Pb + pB * PLANE + cj  * CC;
    const float* rC  = Pb + pC * PLANE + cj  * CC;
    const float* rDp = Pb + pD * PLANE + cj  * CC;
    const float* rm0 = Pb + pB * PLANE + cjm * CC;
    const float* rp0 = Pb + pB * PLANE + cjp * CC;
    const float* rm1 = Pb + pC * PLANE + cjm * CC;
    const float* rp1 = Pb + pC * PLANE + cjp * CC;

    const int idx0 = ((b * SS + i0) * RR + j) * CC + k0;   // unclamped
    const int idx1 = idx0 + PLANE;

    // ---- issue ALL loads up-front (16 independent memory ops) ----
    v4f vA = *(const v4f*)(rA  + k0);
    v4f vB = *(const v4f*)(rB  + k0);
    v4f vC = *(const v4f*)(rC  + k0);
    v4f vDp = *(const v4f*)(rDp + k0);
    v4f m0 = *(const v4f*)(rm0 + k0);
    v4f p0 = *(const v4f*)(rp0 + k0);
    v4f m1 = *(const v4f*)(rm1 + k0);
    v4f p1 = *(const v4f*)(rp1 + k0);
    const float Bcm = rB[kcm];
    const float Bcp = rB[kcp];
    const float Ccm = rC[kcm];
    const float Ccp = rC[kcp];
    v4f d0 = __builtin_nontemporal_load((const v4f*)(D + idx0));
    v4f d1 = __builtin_nontemporal_load((const v4f*)(D + idx1));

    // ---- k-edge fixups ----
    vA = fix4(vA, e0, e1);
    vDp = fix4(vDp, e0, e1);
    m0 = fix4(m0, e0, e1);  p0 = fix4(p0, e0, e1);
    m1 = fix4(m1, e0, e1);  p1 = fix4(p1, e0, e1);

    const float Bw1 = e0 ? vB.y : vB.x;
    const float Bw2 = vB.y;
    const float Bw3 = vB.z;
    const float Bw4 = e1 ? vB.z : vB.w;
    const float Cw1 = e0 ? vC.y : vC.x;
    const float Cw2 = vC.y;
    const float Cw3 = vC.z;
    const float Cw4 = e1 ? vC.z : vC.w;

    // ---- output at i0: Sm = A, center = B-window, Sp = C-window ----
    v4f o0;
    o0.x = stencil_pt(Bw1, vA.x, Cw1, m0.x, p0.x, Bcm, Bw2, d0.x);
    o0.y = stencil_pt(Bw2, vA.y, Cw2, m0.y, p0.y, Bw1, Bw3, d0.y);
    o0.z = stencil_pt(Bw3, vA.z, Cw3, m0.z, p0.z, Bw2, Bw4, d0.z);
    o0.w = stencil_pt(Bw4, vA.w, Cw4, m0.w, p0.w, Bw3, Bcp, d0.w);
    __builtin_nontemporal_store(o0, (v4f*)(out + idx0));

    // ---- output at i1: Sm = B-window, center = C-window, Sp = Dp ----
    v4f o1;
    o1.x = stencil_pt(Cw1, Bw1, vDp.x, m1.x, p1.x, Ccm, Cw2, d1.x);
    o1.y = stencil_pt(Cw2, Bw2, vDp.y, m1.y, p1.y, Cw1, Cw3, d1.y);
    o1.z = stencil_pt(Cw3, Bw3, vDp.z, m1.z, p1.z, Cw2, Cw4, d1.z);
    o1.w = stencil_pt(Cw4, Bw4, vDp.w, m1.w, p1.w, Cw3, Ccp, d1.w);
    __builtin_nontemporal_store(o1, (v4f*)(out + idx1));
}

extern "C" void kernel_launch(void* const* d_in, const int* in_sizes, int n_in,
                              void* d_out, int out_size, void* d_ws, size_t ws_size,
                              hipStream_t stream) {
    const float* P = (const float*)d_in[1];
    const float* D = (const float*)d_in[2];
    float* out = (float*)d_out;

    dim3 block(48, 4, 1);                  // 192 threads = 3 waves
    dim3 grid(1, RR / 4, BB * SS / 2);     // 48 x 512 = 24576 blocks
    flowp_kernel<<<grid, block, 0, stream>>>(P, D, out);
}